// Round 8
// baseline (468.634 us; speedup 1.0000x reference)
//
#include <hip/hip_runtime.h>
#include <hip/hip_bf16.h>
#include <math.h>

#define NN 50000
#define NE 800000
#define HD 128
#define NB 196        // coarse buckets: id >> 8  (196*256 = 50176 >= NN)
#define CAP 5120      // per-bucket edge capacity (avg 4082, +16 sigma)
#define B1_EPB 1024   // edges per block in bucket_kernel

typedef __attribute__((ext_vector_type(8))) short bf16x8v;   // 8 bf16 (4 VGPRs)
typedef __attribute__((ext_vector_type(4))) float f32x4v;    // MFMA acc

static __device__ __forceinline__ unsigned short f2bf(float x) {
    union { float f; unsigned u; } v; v.f = x;
    unsigned r = v.u + 0x7fff + ((v.u >> 16) & 1);   // RNE
    return (unsigned short)(r >> 16);
}

// hs / aggb live in SLICED layout: [slice(4)][node(NN)][32 bf16]
// so that each 3.2MB slice fits a 4MiB per-XCD L2.

// ---------------- B1: coarse bucket scatter (dst-major pairs + src ids) ----------------
__global__ __launch_bounds__(256) void bucket_kernel(const int* __restrict__ src,
                                                     const int* __restrict__ dst,
                                                     int* __restrict__ dcur,
                                                     int* __restrict__ scur,
                                                     int2* __restrict__ dbucket,
                                                     int* __restrict__ sbucket) {
    __shared__ int hd[NB], hsb[NB], cd[NB], cs[NB];
    int t = threadIdx.x;
    if (t < NB) { hd[t] = 0; hsb[t] = 0; }
    __syncthreads();
    int d[4], s[4];
    int e0 = blockIdx.x * B1_EPB + t;
    #pragma unroll
    for (int j = 0; j < 4; ++j) {
        int e = e0 + j * 256;
        if (e < NE) {
            d[j] = dst[e]; s[j] = src[e];
            atomicAdd(&hd[d[j] >> 8], 1);
            atomicAdd(&hsb[s[j] >> 8], 1);
        } else d[j] = -1;
    }
    __syncthreads();
    if (t < NB) {
        cd[t] = atomicAdd(&dcur[t], hd[t]);
        cs[t] = atomicAdd(&scur[t], hsb[t]);
    }
    __syncthreads();
    #pragma unroll
    for (int j = 0; j < 4; ++j) {
        if (d[j] >= 0) {
            int b = d[j] >> 8;
            int p = atomicAdd(&cd[b], 1);
            if (p < CAP) dbucket[(long)b * CAP + p] = make_int2(d[j], s[j]);
            int bs = s[j] >> 8;
            int p2 = atomicAdd(&cs[bs], 1);
            if (p2 < CAP) sbucket[(long)bs * CAP + p2] = s[j];
        }
    }
}

// ---------------- B2: per-bucket histogram+scan -> compact CSR ----------------
__global__ __launch_bounds__(256) void csr_dst_kernel(const int2* __restrict__ dbucket,
                                                      const int* __restrict__ dcur,
                                                      int* __restrict__ row_ptr,
                                                      int* __restrict__ col) {
    __shared__ int buf[256];
    __shared__ int hist[256];
    __shared__ int cur[256];
    int k = blockIdx.x, t = threadIdx.x;

    int tot = (t < NB) ? min(dcur[t], CAP) : 0;
    buf[t] = tot;
    __syncthreads();
    for (int o = 1; o < 256; o <<= 1) {
        int a = (t >= o) ? buf[t - o] : 0;
        __syncthreads();
        buf[t] += a;
        __syncthreads();
    }
    int base = (k > 0) ? buf[k - 1] : 0;
    int cnt = min(dcur[k], CAP);

    hist[t] = 0;
    __syncthreads();
    const int2* bk = dbucket + (long)k * CAP;
    for (int e = t; e < cnt; e += 256) atomicAdd(&hist[bk[e].x & 255], 1);
    __syncthreads();
    int h = hist[t];

    buf[t] = h;
    __syncthreads();
    for (int o = 1; o < 256; o <<= 1) {
        int a = (t >= o) ? buf[t - o] : 0;
        __syncthreads();
        buf[t] += a;
        __syncthreads();
    }
    int start = base + buf[t] - h;
    int id = (k << 8) + t;
    if (id < NN) row_ptr[id] = start;
    if (k == NB - 1 && t == 0) row_ptr[NN] = base + cnt;
    cur[t] = start;
    __syncthreads();

    for (int e = t; e < cnt; e += 256) {
        int2 p = bk[e];
        int pos = atomicAdd(&cur[p.x & 255], 1);
        col[pos] = p.y;
    }
}

// ---------------- B3: per-bucket src histogram -> out_cnt ----------------
__global__ __launch_bounds__(256) void outdeg_kernel(const int* __restrict__ sbucket,
                                                     const int* __restrict__ scur,
                                                     int* __restrict__ out_cnt) {
    __shared__ int hist[256];
    int k = blockIdx.x, t = threadIdx.x;
    hist[t] = 0;
    __syncthreads();
    int cnt = min(scur[k], CAP);
    const int* bk = sbucket + (long)k * CAP;
    for (int e = t; e < cnt; e += 256) atomicAdd(&hist[bk[e] & 255], 1);
    __syncthreads();
    int id = (k << 8) + t;
    if (id < NN) out_cnt[id] = hist[t];
}

// ---------------- node init: norms + h0 pre-scaled by norm_s ----------------
__global__ __launch_bounds__(256) void node_init_kernel(const float* __restrict__ cx,
                                                        const float* __restrict__ cy,
                                                        const int* __restrict__ row_ptr,
                                                        const int* __restrict__ out_cnt,
                                                        float* __restrict__ norm_s,
                                                        float* __restrict__ norm_d,
                                                        float* __restrict__ h0s) {
    int i = blockIdx.x * 256 + threadIdx.x;
    if (i < NN) {
        float id = (float)(row_ptr[i + 1] - row_ptr[i]);
        float od = (float)out_cnt[i];
        float ns = 1.0f / sqrtf(fmaxf(od, 1.0f));
        norm_s[i] = ns;
        norm_d[i] = 1.0f / sqrtf(fmaxf(id, 1.0f));
        h0s[i * 3 + 0] = id * ns;
        h0s[i * 3 + 1] = cx[i] * ns;
        h0s[i * 3 + 2] = cy[i] * ns;
    }
}

// ---------------- W2..W5 -> bf16, transposed: Wt[l][n][k] = bf16(W[k][n]) ----------------
__global__ __launch_bounds__(256) void convw_kernel(const float* __restrict__ W2,
                                                    const float* __restrict__ W3,
                                                    const float* __restrict__ W4,
                                                    const float* __restrict__ W5,
                                                    unsigned short* __restrict__ Wt) {
    int gid = blockIdx.x * 256 + threadIdx.x;
    if (gid < 4 * 16384) {
        int l = gid >> 14, idx = gid & 16383;
        int n = idx >> 7, k = idx & 127;
        const float* W = (l == 0) ? W2 : (l == 1) ? W3 : (l == 2) ? W4 : W5;
        Wt[gid] = f2bf(W[k * 128 + n]);
    }
}

// ---------------- layer-1 gather (F=3), compact CSR ----------------
__global__ __launch_bounds__(256) void gather3_kernel(const int* __restrict__ row_ptr,
                                                      const int* __restrict__ col,
                                                      const float* __restrict__ h0s,
                                                      const float* __restrict__ norm_d,
                                                      float* __restrict__ agg3) {
    int n = blockIdx.x * 256 + threadIdx.x;
    if (n < NN) {
        float a0 = 0.f, a1 = 0.f, a2 = 0.f;
        int end = row_ptr[n + 1];
        for (int e = row_ptr[n]; e < end; ++e) {
            int s = col[e];
            a0 += h0s[s * 3 + 0];
            a1 += h0s[s * 3 + 1];
            a2 += h0s[s * 3 + 2];
        }
        float nd = norm_d[n];
        agg3[n * 3 + 0] = a0 * nd;
        agg3[n * 3 + 1] = a1 * nd;
        agg3[n * 3 + 2] = a2 * nd;
    }
}

// ---------------- layer-1 node (3 -> 128), bf16 sliced out, pre-scaled by norm_s ----------------
__global__ __launch_bounds__(256) void node3_kernel(const float* __restrict__ agg3,
                                                    const float* __restrict__ norm_s,
                                                    const float* __restrict__ W1,
                                                    const float* __restrict__ b1,
                                                    unsigned short* __restrict__ h1s) {
    int gid = blockIdx.x * 256 + threadIdx.x;
    int i = gid >> 7, c = gid & 127;
    if (i < NN) {
        float a0 = agg3[i * 3 + 0];
        float a1 = agg3[i * 3 + 1];
        float a2 = agg3[i * 3 + 2];
        float v = a0 * W1[c] + a1 * W1[128 + c] + a2 * W1[256 + c] + b1[c];
        h1s[((long)(c >> 5) * NN + i) * 32 + (c & 31)] = f2bf(fmaxf(v, 0.0f) * norm_s[i]);
    }
}

// ---------------- sliced edge aggregation: one wave = (node, slice), 4 edges/iter ----------------
// slice = (blockIdx%8)>>1 pins each 3.2MB hs-slice to one XCD pair's L2.
// lane = sub*16 + f: sub in [0,4) picks edge, f in [0,16) picks feature dword.
__global__ __launch_bounds__(256) void gather_sliced_kernel(const int* __restrict__ row_ptr,
                                                            const int* __restrict__ col,
                                                            const unsigned int* __restrict__ hs2,
                                                            const float* __restrict__ norm_d,
                                                            unsigned int* __restrict__ aggb2) {
    int bid = blockIdx.x;
    int slice = (bid & 7) >> 1;                       // XCD pair -> slice
    int grp = (bid >> 3) * 2 + (bid & 1);             // [0, 12500)
    int t = threadIdx.x;
    int wave = t >> 6, lane = t & 63;
    int n = grp * 4 + wave;                           // [0, 50000)
    int sub = lane >> 4, f = lane & 15;

    int beg = row_ptr[n], end = row_ptr[n + 1];
    const unsigned int* hb = hs2 + (long)slice * NN * 16 + f;   // node stride 16 dwords
    float ax = 0.f, ay = 0.f;
    int e = beg + sub;
    for (; e + 4 < end; e += 8) {                     // 2 masked-free iters (e, e+4 valid)
        int s0 = col[e], s1 = col[e + 4];
        unsigned u0 = hb[(long)s0 << 4];
        unsigned u1 = hb[(long)s1 << 4];
        ax += __uint_as_float(u0 << 16) + __uint_as_float(u1 << 16);
        ay += __uint_as_float(u0 & 0xffff0000u) + __uint_as_float(u1 & 0xffff0000u);
    }
    if (e < end) {
        unsigned u0 = hb[(long)col[e] << 4];
        ax += __uint_as_float(u0 << 16);
        ay += __uint_as_float(u0 & 0xffff0000u);
    }
    // reduce across the 4 sub-groups (features align at lane xor 16/32)
    ax += __shfl_xor(ax, 16); ay += __shfl_xor(ay, 16);
    ax += __shfl_xor(ax, 32); ay += __shfl_xor(ay, 32);
    if (sub == 0) {
        float nd = norm_d[n];
        unsigned po = (unsigned)f2bf(ax * nd) | ((unsigned)f2bf(ay * nd) << 16);
        aggb2[((long)slice * NN + n) * 16 + f] = po;
    }
}

// ---------------- node GEMM via MFMA bf16 (sliced A, sliced bf16 out / dense fp32 out) ----------------
// D mapping (m89-verified): col = lane&15, row = (lane>>4)*4 + reg.
__global__ __launch_bounds__(256) void gemm_mfma_kernel(const unsigned short* __restrict__ aggb,
                                                        const float* __restrict__ scale,
                                                        const unsigned short* __restrict__ Wt,
                                                        const float* __restrict__ bias,
                                                        unsigned short* __restrict__ out_bf,
                                                        float* __restrict__ out_f32,
                                                        float* __restrict__ embsum) {
    __shared__ unsigned short ldsw[128][136];
    __shared__ float ldscol[4][4][128];

    int t = threadIdx.x;
    int wv = t >> 6, lane = t & 63;
    int fr = lane & 15, kq = lane >> 4;
    int m0 = blockIdx.x * 64 + wv * 16;

    #pragma unroll
    for (int i = 0; i < 8; ++i) {
        int idx = t + 256 * i;
        int r = idx >> 4;
        int c8 = (idx & 15) << 3;
        *(bf16x8v*)(&ldsw[r][c8]) = *(const bf16x8v*)(Wt + (r << 7) + c8);
    }

    int mrow = m0 + fr;
    long mr_ = (mrow < NN) ? mrow : 0;
    bf16x8v a0 = *(const bf16x8v*)(aggb + (0L * NN + mr_) * 32 + kq * 8);
    bf16x8v a1 = *(const bf16x8v*)(aggb + (1L * NN + mr_) * 32 + kq * 8);
    bf16x8v a2 = *(const bf16x8v*)(aggb + (2L * NN + mr_) * 32 + kq * 8);
    bf16x8v a3 = *(const bf16x8v*)(aggb + (3L * NN + mr_) * 32 + kq * 8);

    float sc[4];
    #pragma unroll
    for (int r = 0; r < 4; ++r) {
        int mr = m0 + kq * 4 + r;
        sc[r] = (out_bf && mr < NN) ? scale[mr] : 1.0f;
    }

    __syncthreads();

    #pragma unroll
    for (int nt = 0; nt < 8; ++nt) {
        int n0 = nt << 4;
        f32x4v acc = {0.f, 0.f, 0.f, 0.f};
        acc = __builtin_amdgcn_mfma_f32_16x16x32_bf16(a0, *(const bf16x8v*)(&ldsw[n0 + fr][0  + kq * 8]), acc, 0, 0, 0);
        acc = __builtin_amdgcn_mfma_f32_16x16x32_bf16(a1, *(const bf16x8v*)(&ldsw[n0 + fr][32 + kq * 8]), acc, 0, 0, 0);
        acc = __builtin_amdgcn_mfma_f32_16x16x32_bf16(a2, *(const bf16x8v*)(&ldsw[n0 + fr][64 + kq * 8]), acc, 0, 0, 0);
        acc = __builtin_amdgcn_mfma_f32_16x16x32_bf16(a3, *(const bf16x8v*)(&ldsw[n0 + fr][96 + kq * 8]), acc, 0, 0, 0);

        int c = n0 + fr;                       // output column
        long obase = ((long)(c >> 5) * NN) * 32 + (c & 31);   // sliced layout
        float bv = bias[c];
        float cs = 0.f;
        #pragma unroll
        for (int r = 0; r < 4; ++r) {
            int mr = m0 + kq * 4 + r;
            if (mr < NN) {
                float v = fmaxf(acc[r] + bv, 0.f);
                if (out_bf) out_bf[obase + (long)mr * 32] = f2bf(v * sc[r]);
                else        out_f32[((long)mr << 7) + c] = v;
                cs += v;
            }
        }
        if (embsum) ldscol[wv][kq][c] = cs;
    }

    if (embsum) {
        __syncthreads();
        if (t < 128) {
            float s = 0.f;
            #pragma unroll
            for (int w = 0; w < 4; ++w)
                #pragma unroll
                for (int q = 0; q < 4; ++q)
                    s += ldscol[w][q][t];
            atomicAdd(&embsum[t], s);
        }
    }
}

// ---------------- head MLP ----------------
__global__ __launch_bounds__(128) void head_kernel(const float* __restrict__ embsum,
                                                   const float* __restrict__ Wl1,
                                                   const float* __restrict__ bl1,
                                                   const float* __restrict__ Wl2,
                                                   const float* __restrict__ bl2,
                                                   float* __restrict__ d_out) {
    __shared__ float emb[128];
    __shared__ float hemb[64];
    int t = threadIdx.x;
    float e = embsum[t] * (1.0f / (float)NN);
    emb[t] = e;
    d_out[1 + t] = e;
    __syncthreads();
    if (t < 64) {
        float acc = bl1[t];
        for (int k = 0; k < 128; ++k)
            acc += emb[k] * Wl1[k * 64 + t];
        hemb[t] = fmaxf(acc, 0.f);
    }
    __syncthreads();
    if (t == 0) {
        float acc = bl2[0];
        for (int j = 0; j < 64; ++j)
            acc += hemb[j] * Wl2[j];
        d_out[0] = 1.0f / (1.0f + expf(-acc));
    }
}

extern "C" void kernel_launch(void* const* d_in, const int* in_sizes, int n_in,
                              void* d_out, int out_size, void* d_ws, size_t ws_size,
                              hipStream_t stream) {
    const float* cx  = (const float*)d_in[0];
    const float* cy  = (const float*)d_in[1];
    const float* W1  = (const float*)d_in[2];
    const float* b1  = (const float*)d_in[3];
    const float* W2  = (const float*)d_in[4];
    const float* b2  = (const float*)d_in[5];
    const float* W3  = (const float*)d_in[6];
    const float* b3  = (const float*)d_in[7];
    const float* W4  = (const float*)d_in[8];
    const float* b4  = (const float*)d_in[9];
    const float* W5  = (const float*)d_in[10];
    const float* b5  = (const float*)d_in[11];
    const float* Wl1 = (const float*)d_in[12];
    const float* bl1 = (const float*)d_in[13];
    const float* Wl2 = (const float*)d_in[14];
    const float* bl2 = (const float*)d_in[15];
    const int*   src = (const int*)d_in[16];
    const int*   dst = (const int*)d_in[17];

    float* out = (float*)d_out;
    float* h_out = out + 129;

    // workspace layout (float-index units)
    float* ws       = (float*)d_ws;
    float* norm_s   = ws;                                   // N
    float* norm_d   = ws + NN;                              // N
    int*   out_cnt  = (int*)(ws + 2 * NN);                  // N
    int*   row_ptr  = (int*)(ws + 3 * NN);                  // N+1
    unsigned short* hs   = (unsigned short*)(ws + 4 * NN + 64);   // 128N bf16, sliced
    unsigned short* aggb = (unsigned short*)(ws + 68 * NN + 64);  // 128N bf16, sliced
    int*   col      = (int*)(ws + 132 * NN + 64);           // NE
    float* h0s      = ws + 148 * NN + 64;                   // 3N
    float* agg3     = ws + 151 * NN + 64;                   // 3N
    unsigned short* Wt = (unsigned short*)(ws + 154 * NN + 64);   // 4*16384 bf16
    float* embsum   = ws + 154 * NN + 64 + 32768;           // 128
    int*   dcur     = (int*)(ws + 154 * NN + 33600);        // NB
    int*   scur     = dcur + NB;                            // NB
    int2*  dbucket  = (int2*)(ws + 154 * NN + 34048);       // NB*CAP int2
    int*   sbucket  = (int*)(ws + 154 * NN + 34048 + 2 * NB * CAP);  // NB*CAP int

    // 1. two-level bucket CSR build (atomic-light)
    hipMemsetAsync(dcur, 0, 2 * NB * sizeof(int), stream);
    bucket_kernel<<<(NE + B1_EPB - 1) / B1_EPB, 256, 0, stream>>>(src, dst, dcur, scur,
                                                                  dbucket, sbucket);
    csr_dst_kernel<<<NB, 256, 0, stream>>>(dbucket, dcur, row_ptr, col);
    outdeg_kernel<<<NB, 256, 0, stream>>>(sbucket, scur, out_cnt);

    // 2. norms + scaled h0; weight convert (independent)
    node_init_kernel<<<(NN + 255) / 256, 256, 0, stream>>>(cx, cy, row_ptr, out_cnt,
                                                           norm_s, norm_d, h0s);
    convw_kernel<<<256, 256, 0, stream>>>(W2, W3, W4, W5, Wt);

    // 3. layer 1 (F_in = 3)
    gather3_kernel<<<(NN + 255) / 256, 256, 0, stream>>>(row_ptr, col, h0s, norm_d, agg3);
    node3_kernel<<<(NN * 128) / 256, 256, 0, stream>>>(agg3, norm_s, W1, b1, hs);

    // 4. layers 2..5: XCD-sliced bf16 gather + MFMA GEMM (+ fused colsum on last)
    hipMemsetAsync(embsum, 0, 128 * sizeof(float), stream);
    const float* bs[4] = {b2, b3, b4, b5};
    const int gather_blocks = 50000;     // 4 slices x 12500 node-quads
    const int gemm_blocks = (NN + 63) / 64;
    for (int l = 0; l < 4; ++l) {
        gather_sliced_kernel<<<gather_blocks, 256, 0, stream>>>(row_ptr, col,
                                                                (const unsigned int*)hs,
                                                                norm_d,
                                                                (unsigned int*)aggb);
        bool last = (l == 3);
        gemm_mfma_kernel<<<gemm_blocks, 256, 0, stream>>>(
            aggb, norm_s, Wt + l * 16384, bs[l],
            last ? nullptr : hs,
            last ? h_out : nullptr,
            last ? embsum : nullptr);
    }

    // 5. head
    head_kernel<<<1, 128, 0, stream>>>(embsum, Wl1, bl1, Wl2, bl2, out);
}

// Round 9
// 461.370 us; speedup vs baseline: 1.0157x; 1.0157x over previous
//
#include <hip/hip_runtime.h>
#include <hip/hip_bf16.h>
#include <math.h>

#define NN 50000
#define NE 800000
#define HD 128
#define NB 196        // coarse buckets: id >> 8  (196*256 = 50176 >= NN)
#define CAP 5120      // per-bucket edge capacity (avg 4082, +16 sigma)
#define B1_EPB 1024   // edges per block in bucket_kernel

typedef __attribute__((ext_vector_type(8))) short bf16x8v;   // 8 bf16 (4 VGPRs)
typedef __attribute__((ext_vector_type(4))) float f32x4v;    // MFMA acc

static __device__ __forceinline__ unsigned short f2bf(float x) {
    union { float f; unsigned u; } v; v.f = x;
    unsigned r = v.u + 0x7fff + ((v.u >> 16) & 1);   // RNE
    return (unsigned short)(r >> 16);
}

// hs / aggb live in SLICED layout: [slice(4)][node(NN)][32 bf16]
// so each 3.2MB slice fits one XCD's 4MiB L2 (pinning via blockIdx%8 -> XCD).

// ---------------- B1: coarse bucket scatter (dst-major pairs + src ids) ----------------
__global__ __launch_bounds__(256) void bucket_kernel(const int* __restrict__ src,
                                                     const int* __restrict__ dst,
                                                     int* __restrict__ dcur,
                                                     int* __restrict__ scur,
                                                     int2* __restrict__ dbucket,
                                                     int* __restrict__ sbucket) {
    __shared__ int hd[NB], hsb[NB], cd[NB], cs[NB];
    int t = threadIdx.x;
    if (t < NB) { hd[t] = 0; hsb[t] = 0; }
    __syncthreads();
    int d[4], s[4];
    int e0 = blockIdx.x * B1_EPB + t;
    #pragma unroll
    for (int j = 0; j < 4; ++j) {
        int e = e0 + j * 256;
        if (e < NE) {
            d[j] = dst[e]; s[j] = src[e];
            atomicAdd(&hd[d[j] >> 8], 1);
            atomicAdd(&hsb[s[j] >> 8], 1);
        } else d[j] = -1;
    }
    __syncthreads();
    if (t < NB) {
        cd[t] = atomicAdd(&dcur[t], hd[t]);
        cs[t] = atomicAdd(&scur[t], hsb[t]);
    }
    __syncthreads();
    #pragma unroll
    for (int j = 0; j < 4; ++j) {
        if (d[j] >= 0) {
            int b = d[j] >> 8;
            int p = atomicAdd(&cd[b], 1);
            if (p < CAP) dbucket[(long)b * CAP + p] = make_int2(d[j], s[j]);
            int bs = s[j] >> 8;
            int p2 = atomicAdd(&cs[bs], 1);
            if (p2 < CAP) sbucket[(long)bs * CAP + p2] = s[j];
        }
    }
}

// ---------------- B2+B3 merged: compact CSR + out-degree histogram ----------------
__global__ __launch_bounds__(256) void csr_out_kernel(const int2* __restrict__ dbucket,
                                                      const int* __restrict__ dcur,
                                                      const int* __restrict__ sbucket,
                                                      const int* __restrict__ scur,
                                                      int* __restrict__ row_ptr,
                                                      int* __restrict__ col,
                                                      int* __restrict__ out_cnt) {
    __shared__ int buf[256];
    __shared__ int hist[256];
    __shared__ int cur[256];
    int k = blockIdx.x, t = threadIdx.x;

    // global base for this bucket: scan of all bucket totals
    int tot = (t < NB) ? min(dcur[t], CAP) : 0;
    buf[t] = tot;
    __syncthreads();
    for (int o = 1; o < 256; o <<= 1) {
        int a = (t >= o) ? buf[t - o] : 0;
        __syncthreads();
        buf[t] += a;
        __syncthreads();
    }
    int base = (k > 0) ? buf[k - 1] : 0;
    int cnt = min(dcur[k], CAP);

    // 256-bin histogram of dst & 255
    hist[t] = 0;
    __syncthreads();
    const int2* bk = dbucket + (long)k * CAP;
    for (int e = t; e < cnt; e += 256) atomicAdd(&hist[bk[e].x & 255], 1);
    __syncthreads();
    int h = hist[t];

    buf[t] = h;
    __syncthreads();
    for (int o = 1; o < 256; o <<= 1) {
        int a = (t >= o) ? buf[t - o] : 0;
        __syncthreads();
        buf[t] += a;
        __syncthreads();
    }
    int start = base + buf[t] - h;
    int id = (k << 8) + t;
    if (id < NN) row_ptr[id] = start;
    if (k == NB - 1 && t == 0) row_ptr[NN] = base + cnt;
    cur[t] = start;
    __syncthreads();

    for (int e = t; e < cnt; e += 256) {
        int2 p = bk[e];
        int pos = atomicAdd(&cur[p.x & 255], 1);
        col[pos] = p.y;
    }

    // ---- out-degree histogram over src bucket ----
    __syncthreads();
    hist[t] = 0;
    __syncthreads();
    int scnt = min(scur[k], CAP);
    const int* sk = sbucket + (long)k * CAP;
    for (int e = t; e < scnt; e += 256) atomicAdd(&hist[sk[e] & 255], 1);
    __syncthreads();
    if (id < NN) out_cnt[id] = hist[t];
}

// ---------------- merged node init + weight convert ----------------
__global__ __launch_bounds__(256) void initw_kernel(const float* __restrict__ cx,
                                                    const float* __restrict__ cy,
                                                    const int* __restrict__ row_ptr,
                                                    const int* __restrict__ out_cnt,
                                                    const float* __restrict__ W2,
                                                    const float* __restrict__ W3,
                                                    const float* __restrict__ W4,
                                                    const float* __restrict__ W5,
                                                    float* __restrict__ norm_s,
                                                    float* __restrict__ norm_d,
                                                    float* __restrict__ h0s,
                                                    unsigned short* __restrict__ Wt) {
    int bid = blockIdx.x, t = threadIdx.x;
    if (bid < NB) {
        int i = (bid << 8) + t;
        if (i < NN) {
            float id = (float)(row_ptr[i + 1] - row_ptr[i]);
            float od = (float)out_cnt[i];
            float ns = 1.0f / sqrtf(fmaxf(od, 1.0f));
            norm_s[i] = ns;
            norm_d[i] = 1.0f / sqrtf(fmaxf(id, 1.0f));
            h0s[i * 3 + 0] = id * ns;
            h0s[i * 3 + 1] = cx[i] * ns;
            h0s[i * 3 + 2] = cy[i] * ns;
        }
    } else {
        int gid = ((bid - NB) << 8) + t;     // < 65536
        int l = gid >> 14, idx = gid & 16383;
        int n = idx >> 7, k = idx & 127;
        const float* W = (l == 0) ? W2 : (l == 1) ? W3 : (l == 2) ? W4 : W5;
        Wt[gid] = f2bf(W[k * 128 + n]);
    }
}

// ---------------- layer-1 gather (F=3), compact CSR ----------------
__global__ __launch_bounds__(256) void gather3_kernel(const int* __restrict__ row_ptr,
                                                      const int* __restrict__ col,
                                                      const float* __restrict__ h0s,
                                                      const float* __restrict__ norm_d,
                                                      float* __restrict__ agg3) {
    int n = blockIdx.x * 256 + threadIdx.x;
    if (n < NN) {
        float a0 = 0.f, a1 = 0.f, a2 = 0.f;
        int end = row_ptr[n + 1];
        for (int e = row_ptr[n]; e < end; ++e) {
            int s = col[e];
            a0 += h0s[s * 3 + 0];
            a1 += h0s[s * 3 + 1];
            a2 += h0s[s * 3 + 2];
        }
        float nd = norm_d[n];
        agg3[n * 3 + 0] = a0 * nd;
        agg3[n * 3 + 1] = a1 * nd;
        agg3[n * 3 + 2] = a2 * nd;
    }
}

// ---------------- layer-1 node (3 -> 128), bf16 sliced out, pre-scaled by norm_s ----------------
__global__ __launch_bounds__(256) void node3_kernel(const float* __restrict__ agg3,
                                                    const float* __restrict__ norm_s,
                                                    const float* __restrict__ W1,
                                                    const float* __restrict__ b1,
                                                    unsigned short* __restrict__ h1s) {
    int gid = blockIdx.x * 256 + threadIdx.x;
    int i = gid >> 7, c = gid & 127;
    if (i < NN) {
        float a0 = agg3[i * 3 + 0];
        float a1 = agg3[i * 3 + 1];
        float a2 = agg3[i * 3 + 2];
        float v = a0 * W1[c] + a1 * W1[128 + c] + a2 * W1[256 + c] + b1[c];
        h1s[((long)(c >> 5) * NN + i) * 32 + (c & 31)] = f2bf(fmaxf(v, 0.0f) * norm_s[i]);
    }
}

// ---------------- sliced edge aggregation v2: wave-uniform e, q-broadcast col ----------------
// slice = (blockIdx%8)>>1 pins each 3.2MB hs-slice to one XCD pair's L2.
// q = lane>>4 picks edge within a 4-edge pack via col[e+q] (ONE broadcast load),
// f = lane&15 picks the feature dword. e stays wave-uniform -> tight loop.
__global__ __launch_bounds__(256) void gather_sliced_kernel(const int* __restrict__ row_ptr,
                                                            const int* __restrict__ col,
                                                            const unsigned int* __restrict__ hs2,
                                                            const float* __restrict__ norm_d,
                                                            unsigned int* __restrict__ aggb2) {
    int bid = blockIdx.x;
    int slice = (bid & 7) >> 1;                       // XCD pair -> slice
    int grp = (bid >> 3) * 2 + (bid & 1);             // [0, 12500)
    int t = threadIdx.x;
    int wave = t >> 6, lane = t & 63;
    int n = grp * 4 + wave;                           // [0, 50000)
    int q = lane >> 4, f = lane & 15;

    int beg = row_ptr[n], end = row_ptr[n + 1];
    const unsigned int* hb = hs2 + (long)slice * NN * 16 + f;   // node stride 16 dw
    const int* colq = col + q;
    float ax = 0.f, ay = 0.f;
    int e = beg;
    for (; e + 7 < end; e += 8) {                     // 8 edges: 2 col + 2 hs loads
        int c0 = colq[e];
        int c1 = colq[e + 4];
        unsigned u0 = hb[(long)c0 << 4];
        unsigned u1 = hb[(long)c1 << 4];
        ax += __uint_as_float(u0 << 16) + __uint_as_float(u1 << 16);
        ay += __uint_as_float(u0 & 0xffff0000u) + __uint_as_float(u1 & 0xffff0000u);
    }
    for (; e < end; e += 4) {                         // tail: clamp + mask
        int eq = e + q;
        int idx = (eq < end) ? eq : (end - 1);
        unsigned u = hb[(long)col[idx] << 4];
        u = (eq < end) ? u : 0u;
        ax += __uint_as_float(u << 16);
        ay += __uint_as_float(u & 0xffff0000u);
    }
    // reduce across the 4 q-groups (same f at lane xor 16/32)
    ax += __shfl_xor(ax, 16); ay += __shfl_xor(ay, 16);
    ax += __shfl_xor(ax, 32); ay += __shfl_xor(ay, 32);
    if (q == 0) {
        float nd = norm_d[n];
        unsigned po = (unsigned)f2bf(ax * nd) | ((unsigned)f2bf(ay * nd) << 16);
        aggb2[((long)slice * NN + n) * 16 + f] = po;
    }
}

// ---------------- node GEMM via MFMA bf16 (sliced A, sliced bf16 out / dense fp32 out) ----------------
// D mapping (m89-verified): col = lane&15, row = (lane>>4)*4 + reg.
__global__ __launch_bounds__(256) void gemm_mfma_kernel(const unsigned short* __restrict__ aggb,
                                                        const float* __restrict__ scale,
                                                        const unsigned short* __restrict__ Wt,
                                                        const float* __restrict__ bias,
                                                        unsigned short* __restrict__ out_bf,
                                                        float* __restrict__ out_f32,
                                                        float* __restrict__ embsum) {
    __shared__ unsigned short ldsw[128][136];
    __shared__ float ldscol[4][4][128];

    int t = threadIdx.x;
    int wv = t >> 6, lane = t & 63;
    int fr = lane & 15, kq = lane >> 4;
    int m0 = blockIdx.x * 64 + wv * 16;

    #pragma unroll
    for (int i = 0; i < 8; ++i) {
        int idx = t + 256 * i;
        int r = idx >> 4;
        int c8 = (idx & 15) << 3;
        *(bf16x8v*)(&ldsw[r][c8]) = *(const bf16x8v*)(Wt + (r << 7) + c8);
    }

    int mrow = m0 + fr;
    long mr_ = (mrow < NN) ? mrow : 0;
    bf16x8v a0 = *(const bf16x8v*)(aggb + (0L * NN + mr_) * 32 + kq * 8);
    bf16x8v a1 = *(const bf16x8v*)(aggb + (1L * NN + mr_) * 32 + kq * 8);
    bf16x8v a2 = *(const bf16x8v*)(aggb + (2L * NN + mr_) * 32 + kq * 8);
    bf16x8v a3 = *(const bf16x8v*)(aggb + (3L * NN + mr_) * 32 + kq * 8);

    float sc[4];
    #pragma unroll
    for (int r = 0; r < 4; ++r) {
        int mr = m0 + kq * 4 + r;
        sc[r] = (out_bf && mr < NN) ? scale[mr] : 1.0f;
    }

    __syncthreads();

    #pragma unroll
    for (int nt = 0; nt < 8; ++nt) {
        int n0 = nt << 4;
        f32x4v acc = {0.f, 0.f, 0.f, 0.f};
        acc = __builtin_amdgcn_mfma_f32_16x16x32_bf16(a0, *(const bf16x8v*)(&ldsw[n0 + fr][0  + kq * 8]), acc, 0, 0, 0);
        acc = __builtin_amdgcn_mfma_f32_16x16x32_bf16(a1, *(const bf16x8v*)(&ldsw[n0 + fr][32 + kq * 8]), acc, 0, 0, 0);
        acc = __builtin_amdgcn_mfma_f32_16x16x32_bf16(a2, *(const bf16x8v*)(&ldsw[n0 + fr][64 + kq * 8]), acc, 0, 0, 0);
        acc = __builtin_amdgcn_mfma_f32_16x16x32_bf16(a3, *(const bf16x8v*)(&ldsw[n0 + fr][96 + kq * 8]), acc, 0, 0, 0);

        int c = n0 + fr;
        long obase = ((long)(c >> 5) * NN) * 32 + (c & 31);   // sliced layout
        float bv = bias[c];
        float cs = 0.f;
        #pragma unroll
        for (int r = 0; r < 4; ++r) {
            int mr = m0 + kq * 4 + r;
            if (mr < NN) {
                float v = fmaxf(acc[r] + bv, 0.f);
                if (out_bf) out_bf[obase + (long)mr * 32] = f2bf(v * sc[r]);
                else        out_f32[((long)mr << 7) + c] = v;
                cs += v;
            }
        }
        if (embsum) ldscol[wv][kq][c] = cs;
    }

    if (embsum) {
        __syncthreads();
        if (t < 128) {
            float s = 0.f;
            #pragma unroll
            for (int w = 0; w < 4; ++w)
                #pragma unroll
                for (int q = 0; q < 4; ++q)
                    s += ldscol[w][q][t];
            atomicAdd(&embsum[t], s);
        }
    }
}

// ---------------- head MLP ----------------
__global__ __launch_bounds__(128) void head_kernel(const float* __restrict__ embsum,
                                                   const float* __restrict__ Wl1,
                                                   const float* __restrict__ bl1,
                                                   const float* __restrict__ Wl2,
                                                   const float* __restrict__ bl2,
                                                   float* __restrict__ d_out) {
    __shared__ float emb[128];
    __shared__ float hemb[64];
    int t = threadIdx.x;
    float e = embsum[t] * (1.0f / (float)NN);
    emb[t] = e;
    d_out[1 + t] = e;
    __syncthreads();
    if (t < 64) {
        float acc = bl1[t];
        for (int k = 0; k < 128; ++k)
            acc += emb[k] * Wl1[k * 64 + t];
        hemb[t] = fmaxf(acc, 0.f);
    }
    __syncthreads();
    if (t == 0) {
        float acc = bl2[0];
        for (int j = 0; j < 64; ++j)
            acc += hemb[j] * Wl2[j];
        d_out[0] = 1.0f / (1.0f + expf(-acc));
    }
}

extern "C" void kernel_launch(void* const* d_in, const int* in_sizes, int n_in,
                              void* d_out, int out_size, void* d_ws, size_t ws_size,
                              hipStream_t stream) {
    const float* cx  = (const float*)d_in[0];
    const float* cy  = (const float*)d_in[1];
    const float* W1  = (const float*)d_in[2];
    const float* b1  = (const float*)d_in[3];
    const float* W2  = (const float*)d_in[4];
    const float* b2  = (const float*)d_in[5];
    const float* W3  = (const float*)d_in[6];
    const float* b3  = (const float*)d_in[7];
    const float* W4  = (const float*)d_in[8];
    const float* b4  = (const float*)d_in[9];
    const float* W5  = (const float*)d_in[10];
    const float* b5  = (const float*)d_in[11];
    const float* Wl1 = (const float*)d_in[12];
    const float* bl1 = (const float*)d_in[13];
    const float* Wl2 = (const float*)d_in[14];
    const float* bl2 = (const float*)d_in[15];
    const int*   src = (const int*)d_in[16];
    const int*   dst = (const int*)d_in[17];

    float* out = (float*)d_out;
    float* h_out = out + 129;

    // workspace layout (float-index units)
    float* ws       = (float*)d_ws;
    float* norm_s   = ws;                                   // N
    float* norm_d   = ws + NN;                              // N
    int*   out_cnt  = (int*)(ws + 2 * NN);                  // N
    int*   row_ptr  = (int*)(ws + 3 * NN);                  // N+1
    unsigned short* hs   = (unsigned short*)(ws + 4 * NN + 64);   // 128N bf16, sliced
    unsigned short* aggb = (unsigned short*)(ws + 68 * NN + 64);  // 128N bf16, sliced
    int*   col      = (int*)(ws + 132 * NN + 64);           // NE
    float* h0s      = ws + 148 * NN + 64;                   // 3N
    float* agg3     = ws + 151 * NN + 64;                   // 3N
    unsigned short* Wt = (unsigned short*)(ws + 154 * NN + 64);   // 4*16384 bf16
    float* embsum   = ws + 154 * NN + 64 + 32768;           // 128
    int*   dcur     = (int*)(ws + 154 * NN + 33600);        // NB
    int*   scur     = dcur + NB;                            // NB
    int2*  dbucket  = (int2*)(ws + 154 * NN + 34048);       // NB*CAP int2
    int*   sbucket  = (int*)(ws + 154 * NN + 34048 + 2 * NB * CAP);  // NB*CAP int

    // 1. two-level bucket CSR build (atomic-light)
    hipMemsetAsync(dcur, 0, 2 * NB * sizeof(int), stream);
    bucket_kernel<<<(NE + B1_EPB - 1) / B1_EPB, 256, 0, stream>>>(src, dst, dcur, scur,
                                                                  dbucket, sbucket);
    csr_out_kernel<<<NB, 256, 0, stream>>>(dbucket, dcur, sbucket, scur,
                                           row_ptr, col, out_cnt);

    // 2. norms + scaled h0 + weight convert (merged)
    initw_kernel<<<NB + 256, 256, 0, stream>>>(cx, cy, row_ptr, out_cnt,
                                               W2, W3, W4, W5,
                                               norm_s, norm_d, h0s, Wt);

    // 3. layer 1 (F_in = 3)
    gather3_kernel<<<(NN + 255) / 256, 256, 0, stream>>>(row_ptr, col, h0s, norm_d, agg3);
    node3_kernel<<<(NN * 128) / 256, 256, 0, stream>>>(agg3, norm_s, W1, b1, hs);

    // 4. layers 2..5: XCD-sliced bf16 gather v2 + MFMA GEMM (+ fused colsum on last)
    hipMemsetAsync(embsum, 0, 128 * sizeof(float), stream);
    const float* bs[4] = {b2, b3, b4, b5};
    const int gather_blocks = 50000;     // 4 slices x 12500 node-quads
    const int gemm_blocks = (NN + 63) / 64;
    for (int l = 0; l < 4; ++l) {
        gather_sliced_kernel<<<gather_blocks, 256, 0, stream>>>(row_ptr, col,
                                                                (const unsigned int*)hs,
                                                                norm_d,
                                                                (unsigned int*)aggb);
        bool last = (l == 3);
        gemm_mfma_kernel<<<gemm_blocks, 256, 0, stream>>>(
            aggb, norm_s, Wt + l * 16384, bs[l],
            last ? nullptr : hs,
            last ? h_out : nullptr,
            last ? embsum : nullptr);
    }

    // 5. head
    head_kernel<<<1, 128, 0, stream>>>(embsum, Wl1, bl1, Wl2, bl2, out);
}

// Round 10
// 330.340 us; speedup vs baseline: 1.4186x; 1.3967x over previous
//
#include <hip/hip_runtime.h>
#include <hip/hip_bf16.h>
#include <math.h>

#define NN 50000
#define NE 800000
#define HD 128
#define NB 196        // coarse buckets: id >> 8  (196*256 = 50176 >= NN)
#define CAP 5120      // per-bucket edge capacity (avg 4082, +16 sigma)
#define B1_EPB 1024   // edges per block in bucket_kernel

typedef __attribute__((ext_vector_type(8))) short bf16x8v;   // 8 bf16 (4 VGPRs)
typedef __attribute__((ext_vector_type(4))) float f32x4v;    // MFMA acc

static __device__ __forceinline__ unsigned short f2bf(float x) {
    union { float f; unsigned u; } v; v.f = x;
    unsigned r = v.u + 0x7fff + ((v.u >> 16) & 1);   // RNE
    return (unsigned short)(r >> 16);
}

// ---------------- B1: coarse bucket scatter (dst-major pairs + src ids) ----------------
__global__ __launch_bounds__(256) void bucket_kernel(const int* __restrict__ src,
                                                     const int* __restrict__ dst,
                                                     int* __restrict__ dcur,
                                                     int* __restrict__ scur,
                                                     int2* __restrict__ dbucket,
                                                     int* __restrict__ sbucket) {
    __shared__ int hd[NB], hsb[NB], cd[NB], cs[NB];
    int t = threadIdx.x;
    if (t < NB) { hd[t] = 0; hsb[t] = 0; }
    __syncthreads();
    int d[4], s[4];
    int e0 = blockIdx.x * B1_EPB + t;
    #pragma unroll
    for (int j = 0; j < 4; ++j) {
        int e = e0 + j * 256;
        if (e < NE) {
            d[j] = dst[e]; s[j] = src[e];
            atomicAdd(&hd[d[j] >> 8], 1);
            atomicAdd(&hsb[s[j] >> 8], 1);
        } else d[j] = -1;
    }
    __syncthreads();
    if (t < NB) {
        cd[t] = atomicAdd(&dcur[t], hd[t]);
        cs[t] = atomicAdd(&scur[t], hsb[t]);
    }
    __syncthreads();
    #pragma unroll
    for (int j = 0; j < 4; ++j) {
        if (d[j] >= 0) {
            int b = d[j] >> 8;
            int p = atomicAdd(&cd[b], 1);
            if (p < CAP) dbucket[(long)b * CAP + p] = make_int2(d[j], s[j]);
            int bs = s[j] >> 8;
            int p2 = atomicAdd(&cs[bs], 1);
            if (p2 < CAP) sbucket[(long)bs * CAP + p2] = s[j];
        }
    }
}

// ---------------- B2+B3 merged: compact CSR + out-degree histogram ----------------
__global__ __launch_bounds__(256) void csr_out_kernel(const int2* __restrict__ dbucket,
                                                      const int* __restrict__ dcur,
                                                      const int* __restrict__ sbucket,
                                                      const int* __restrict__ scur,
                                                      int* __restrict__ row_ptr,
                                                      int* __restrict__ col,
                                                      int* __restrict__ out_cnt) {
    __shared__ int buf[256];
    __shared__ int hist[256];
    __shared__ int cur[256];
    int k = blockIdx.x, t = threadIdx.x;

    // global base for this bucket: scan of all bucket totals
    int tot = (t < NB) ? min(dcur[t], CAP) : 0;
    buf[t] = tot;
    __syncthreads();
    for (int o = 1; o < 256; o <<= 1) {
        int a = (t >= o) ? buf[t - o] : 0;
        __syncthreads();
        buf[t] += a;
        __syncthreads();
    }
    int base = (k > 0) ? buf[k - 1] : 0;
    int cnt = min(dcur[k], CAP);

    // 256-bin histogram of dst & 255
    hist[t] = 0;
    __syncthreads();
    const int2* bk = dbucket + (long)k * CAP;
    for (int e = t; e < cnt; e += 256) atomicAdd(&hist[bk[e].x & 255], 1);
    __syncthreads();
    int h = hist[t];

    buf[t] = h;
    __syncthreads();
    for (int o = 1; o < 256; o <<= 1) {
        int a = (t >= o) ? buf[t - o] : 0;
        __syncthreads();
        buf[t] += a;
        __syncthreads();
    }
    int start = base + buf[t] - h;
    int id = (k << 8) + t;
    if (id < NN) row_ptr[id] = start;
    if (k == NB - 1 && t == 0) row_ptr[NN] = base + cnt;
    cur[t] = start;
    __syncthreads();

    for (int e = t; e < cnt; e += 256) {
        int2 p = bk[e];
        int pos = atomicAdd(&cur[p.x & 255], 1);
        col[pos] = p.y;
    }

    // ---- out-degree histogram over src bucket ----
    __syncthreads();
    hist[t] = 0;
    __syncthreads();
    int scnt = min(scur[k], CAP);
    const int* sk = sbucket + (long)k * CAP;
    for (int e = t; e < scnt; e += 256) atomicAdd(&hist[sk[e] & 255], 1);
    __syncthreads();
    if (id < NN) out_cnt[id] = hist[t];
}

// ---------------- merged node init + weight convert + embsum zero ----------------
__global__ __launch_bounds__(256) void initw_kernel(const float* __restrict__ cx,
                                                    const float* __restrict__ cy,
                                                    const int* __restrict__ row_ptr,
                                                    const int* __restrict__ out_cnt,
                                                    const float* __restrict__ W2,
                                                    const float* __restrict__ W3,
                                                    const float* __restrict__ W4,
                                                    const float* __restrict__ W5,
                                                    float* __restrict__ norm_s,
                                                    float* __restrict__ norm_d,
                                                    float* __restrict__ h0s,
                                                    unsigned short* __restrict__ Wt,
                                                    float* __restrict__ embsum) {
    int bid = blockIdx.x, t = threadIdx.x;
    if (bid < NB) {
        int i = (bid << 8) + t;
        if (i < NN) {
            float id = (float)(row_ptr[i + 1] - row_ptr[i]);
            float od = (float)out_cnt[i];
            float ns = 1.0f / sqrtf(fmaxf(od, 1.0f));
            norm_s[i] = ns;
            norm_d[i] = 1.0f / sqrtf(fmaxf(id, 1.0f));
            h0s[i * 3 + 0] = id * ns;
            h0s[i * 3 + 1] = cx[i] * ns;
            h0s[i * 3 + 2] = cy[i] * ns;
        }
    } else {
        int gid = ((bid - NB) << 8) + t;     // < 65536
        int l = gid >> 14, idx = gid & 16383;
        int n = idx >> 7, k = idx & 127;
        const float* W = (l == 0) ? W2 : (l == 1) ? W3 : (l == 2) ? W4 : W5;
        Wt[gid] = f2bf(W[k * 128 + n]);
        if (bid == NB && t < 128) embsum[t] = 0.0f;
    }
}

// ---------------- layer-1 gather (F=3), compact CSR ----------------
__global__ __launch_bounds__(256) void gather3_kernel(const int* __restrict__ row_ptr,
                                                      const int* __restrict__ col,
                                                      const float* __restrict__ h0s,
                                                      const float* __restrict__ norm_d,
                                                      float* __restrict__ agg3) {
    int n = blockIdx.x * 256 + threadIdx.x;
    if (n < NN) {
        float a0 = 0.f, a1 = 0.f, a2 = 0.f;
        int end = row_ptr[n + 1];
        for (int e = row_ptr[n]; e < end; ++e) {
            int s = col[e];
            a0 += h0s[s * 3 + 0];
            a1 += h0s[s * 3 + 1];
            a2 += h0s[s * 3 + 2];
        }
        float nd = norm_d[n];
        agg3[n * 3 + 0] = a0 * nd;
        agg3[n * 3 + 1] = a1 * nd;
        agg3[n * 3 + 2] = a2 * nd;
    }
}

// ---------------- layer-1 node (3 -> 128), bf16 dense out, pre-scaled by norm_s ----------------
__global__ __launch_bounds__(256) void node3_kernel(const float* __restrict__ agg3,
                                                    const float* __restrict__ norm_s,
                                                    const float* __restrict__ W1,
                                                    const float* __restrict__ b1,
                                                    unsigned short* __restrict__ h1s) {
    int gid = blockIdx.x * 256 + threadIdx.x;
    int i = gid >> 7, c = gid & 127;
    if (i < NN) {
        float a0 = agg3[i * 3 + 0];
        float a1 = agg3[i * 3 + 1];
        float a2 = agg3[i * 3 + 2];
        float v = a0 * W1[c] + a1 * W1[128 + c] + a2 * W1[256 + c] + b1[c];
        h1s[i * 128 + c] = f2bf(fmaxf(v, 0.0f) * norm_s[i]);
    }
}

// ---------------- edge aggregation F=128: bf16 gather, compact CSR (R7-proven) ----------------
// One WAVE per node (wave-uniform edge loop). Lane owns 2 features (1 dword).
__global__ __launch_bounds__(256) void gather_bf16_kernel(const int* __restrict__ row_ptr,
                                                          const int* __restrict__ col,
                                                          const unsigned int* __restrict__ hs2,
                                                          const float* __restrict__ norm_d,
                                                          unsigned int* __restrict__ aggb2) {
    int t = threadIdx.x;
    int wave = t >> 6;
    int lane = t & 63;
    int n = blockIdx.x * 4 + wave;
    if (n >= NN) return;
    int beg = row_ptr[n], end = row_ptr[n + 1];
    float nd = norm_d[n];
    const unsigned int* hb = hs2 + lane;
    float ax = 0.f, ay = 0.f;
    int e = beg;
    for (; e + 7 < end; e += 8) {
        unsigned u[8];
        #pragma unroll
        for (int j = 0; j < 8; ++j) u[j] = hb[(long)col[e + j] << 6];
        #pragma unroll
        for (int j = 0; j < 8; ++j) {
            ax += __uint_as_float(u[j] << 16);
            ay += __uint_as_float(u[j] & 0xffff0000u);
        }
    }
    for (; e < end; ++e) {
        unsigned u0 = hb[(long)col[e] << 6];
        ax += __uint_as_float(u0 << 16);
        ay += __uint_as_float(u0 & 0xffff0000u);
    }
    unsigned po = (unsigned)f2bf(ax * nd) | ((unsigned)f2bf(ay * nd) << 16);
    aggb2[(n << 6) + lane] = po;
}

// ---------------- node GEMM via MFMA bf16 (dense layout, R7-proven) ----------------
// D mapping (m89-verified): col = lane&15, row = (lane>>4)*4 + reg.
__global__ __launch_bounds__(256) void gemm_mfma_kernel(const unsigned short* __restrict__ aggb,
                                                        const float* __restrict__ scale,
                                                        const unsigned short* __restrict__ Wt,
                                                        const float* __restrict__ bias,
                                                        unsigned short* __restrict__ out_bf,
                                                        float* __restrict__ out_f32,
                                                        float* __restrict__ embsum) {
    __shared__ unsigned short ldsw[128][136];
    __shared__ float ldscol[4][4][128];

    int t = threadIdx.x;
    int wv = t >> 6, lane = t & 63;
    int fr = lane & 15, kq = lane >> 4;
    int m0 = blockIdx.x * 64 + wv * 16;

    // stage Wt (32 KB) into LDS, coalesced 16B per lane
    #pragma unroll
    for (int i = 0; i < 8; ++i) {
        int idx = t + 256 * i;
        int r = idx >> 4;
        int c8 = (idx & 15) << 3;
        *(bf16x8v*)(&ldsw[r][c8]) = *(const bf16x8v*)(Wt + (r << 7) + c8);
    }

    int mrow = m0 + fr;
    long abase = (long)((mrow < NN) ? mrow : 0) << 7;
    bf16x8v a0 = *(const bf16x8v*)(aggb + abase + 0  + kq * 8);
    bf16x8v a1 = *(const bf16x8v*)(aggb + abase + 32 + kq * 8);
    bf16x8v a2 = *(const bf16x8v*)(aggb + abase + 64 + kq * 8);
    bf16x8v a3 = *(const bf16x8v*)(aggb + abase + 96 + kq * 8);

    float sc[4];
    #pragma unroll
    for (int r = 0; r < 4; ++r) {
        int mr = m0 + kq * 4 + r;
        sc[r] = (out_bf && mr < NN) ? scale[mr] : 1.0f;
    }

    __syncthreads();

    #pragma unroll
    for (int nt = 0; nt < 8; ++nt) {
        int n0 = nt << 4;
        f32x4v acc = {0.f, 0.f, 0.f, 0.f};
        acc = __builtin_amdgcn_mfma_f32_16x16x32_bf16(a0, *(const bf16x8v*)(&ldsw[n0 + fr][0  + kq * 8]), acc, 0, 0, 0);
        acc = __builtin_amdgcn_mfma_f32_16x16x32_bf16(a1, *(const bf16x8v*)(&ldsw[n0 + fr][32 + kq * 8]), acc, 0, 0, 0);
        acc = __builtin_amdgcn_mfma_f32_16x16x32_bf16(a2, *(const bf16x8v*)(&ldsw[n0 + fr][64 + kq * 8]), acc, 0, 0, 0);
        acc = __builtin_amdgcn_mfma_f32_16x16x32_bf16(a3, *(const bf16x8v*)(&ldsw[n0 + fr][96 + kq * 8]), acc, 0, 0, 0);

        int c = n0 + fr;
        float bv = bias[c];
        float cs = 0.f;
        #pragma unroll
        for (int r = 0; r < 4; ++r) {
            int mr = m0 + kq * 4 + r;
            if (mr < NN) {
                float v = fmaxf(acc[r] + bv, 0.f);
                if (out_bf) out_bf[((long)mr << 7) + c] = f2bf(v * sc[r]);
                else        out_f32[((long)mr << 7) + c] = v;
                cs += v;
            }
        }
        if (embsum) ldscol[wv][kq][c] = cs;
    }

    if (embsum) {
        __syncthreads();
        if (t < 128) {
            float s = 0.f;
            #pragma unroll
            for (int w = 0; w < 4; ++w)
                #pragma unroll
                for (int q = 0; q < 4; ++q)
                    s += ldscol[w][q][t];
            atomicAdd(&embsum[t], s);
        }
    }
}

// ---------------- head MLP ----------------
__global__ __launch_bounds__(128) void head_kernel(const float* __restrict__ embsum,
                                                   const float* __restrict__ Wl1,
                                                   const float* __restrict__ bl1,
                                                   const float* __restrict__ Wl2,
                                                   const float* __restrict__ bl2,
                                                   float* __restrict__ d_out) {
    __shared__ float emb[128];
    __shared__ float hemb[64];
    int t = threadIdx.x;
    float e = embsum[t] * (1.0f / (float)NN);
    emb[t] = e;
    d_out[1 + t] = e;
    __syncthreads();
    if (t < 64) {
        float acc = bl1[t];
        for (int k = 0; k < 128; ++k)
            acc += emb[k] * Wl1[k * 64 + t];
        hemb[t] = fmaxf(acc, 0.f);
    }
    __syncthreads();
    if (t == 0) {
        float acc = bl2[0];
        for (int j = 0; j < 64; ++j)
            acc += hemb[j] * Wl2[j];
        d_out[0] = 1.0f / (1.0f + expf(-acc));
    }
}

extern "C" void kernel_launch(void* const* d_in, const int* in_sizes, int n_in,
                              void* d_out, int out_size, void* d_ws, size_t ws_size,
                              hipStream_t stream) {
    const float* cx  = (const float*)d_in[0];
    const float* cy  = (const float*)d_in[1];
    const float* W1  = (const float*)d_in[2];
    const float* b1  = (const float*)d_in[3];
    const float* W2  = (const float*)d_in[4];
    const float* b2  = (const float*)d_in[5];
    const float* W3  = (const float*)d_in[6];
    const float* b3  = (const float*)d_in[7];
    const float* W4  = (const float*)d_in[8];
    const float* b4  = (const float*)d_in[9];
    const float* W5  = (const float*)d_in[10];
    const float* b5  = (const float*)d_in[11];
    const float* Wl1 = (const float*)d_in[12];
    const float* bl1 = (const float*)d_in[13];
    const float* Wl2 = (const float*)d_in[14];
    const float* bl2 = (const float*)d_in[15];
    const int*   src = (const int*)d_in[16];
    const int*   dst = (const int*)d_in[17];

    float* out = (float*)d_out;
    float* h_out = out + 129;

    // workspace layout (float-index units)
    float* ws       = (float*)d_ws;
    float* norm_s   = ws;                                   // N
    float* norm_d   = ws + NN;                              // N
    int*   out_cnt  = (int*)(ws + 2 * NN);                  // N
    int*   row_ptr  = (int*)(ws + 3 * NN);                  // N+1
    unsigned short* hs   = (unsigned short*)(ws + 4 * NN + 64);   // 128N bf16 dense
    unsigned short* aggb = (unsigned short*)(ws + 68 * NN + 64);  // 128N bf16 dense
    int*   col      = (int*)(ws + 132 * NN + 64);           // NE
    float* h0s      = ws + 148 * NN + 64;                   // 3N
    float* agg3     = ws + 151 * NN + 64;                   // 3N
    unsigned short* Wt = (unsigned short*)(ws + 154 * NN + 64);   // 4*16384 bf16
    float* embsum   = ws + 154 * NN + 64 + 32768;           // 128
    int*   dcur     = (int*)(ws + 154 * NN + 33600);        // NB
    int*   scur     = dcur + NB;                            // NB
    int2*  dbucket  = (int2*)(ws + 154 * NN + 34048);       // NB*CAP int2
    int*   sbucket  = (int*)(ws + 154 * NN + 34048 + 2 * NB * CAP);  // NB*CAP int

    // 1. two-level bucket CSR build (atomic-light)
    hipMemsetAsync(dcur, 0, 2 * NB * sizeof(int), stream);
    bucket_kernel<<<(NE + B1_EPB - 1) / B1_EPB, 256, 0, stream>>>(src, dst, dcur, scur,
                                                                  dbucket, sbucket);
    csr_out_kernel<<<NB, 256, 0, stream>>>(dbucket, dcur, sbucket, scur,
                                           row_ptr, col, out_cnt);

    // 2. norms + scaled h0 + weight convert + embsum zero (merged)
    initw_kernel<<<NB + 256, 256, 0, stream>>>(cx, cy, row_ptr, out_cnt,
                                               W2, W3, W4, W5,
                                               norm_s, norm_d, h0s, Wt, embsum);

    // 3. layer 1 (F_in = 3)
    gather3_kernel<<<(NN + 255) / 256, 256, 0, stream>>>(row_ptr, col, h0s, norm_d, agg3);
    node3_kernel<<<(NN * 128) / 256, 256, 0, stream>>>(agg3, norm_s, W1, b1, hs);

    // 4. layers 2..5: dense bf16 gather (R7-proven) + MFMA GEMM (+ fused colsum on last)
    const float* bs[4] = {b2, b3, b4, b5};
    const int gather_blocks = (NN + 3) / 4;
    const int gemm_blocks = (NN + 63) / 64;
    for (int l = 0; l < 4; ++l) {
        gather_bf16_kernel<<<gather_blocks, 256, 0, stream>>>(row_ptr, col,
                                                              (const unsigned int*)hs,
                                                              norm_d,
                                                              (unsigned int*)aggb);
        bool last = (l == 3);
        gemm_mfma_kernel<<<gemm_blocks, 256, 0, stream>>>(
            aggb, norm_s, Wt + l * 16384, bs[l],
            last ? nullptr : hs,
            last ? h_out : nullptr,
            last ? embsum : nullptr);
    }

    // 5. head
    head_kernel<<<1, 128, 0, stream>>>(embsum, Wl1, bl1, Wl2, bl2, out);
}

// Round 11
// 316.449 us; speedup vs baseline: 1.4809x; 1.0439x over previous
//
#include <hip/hip_runtime.h>
#include <hip/hip_bf16.h>
#include <math.h>

#define NN 50000
#define NE 800000
#define HD 128
#define NB 196        // coarse buckets: id >> 8  (196*256 = 50176 >= NN)
#define CAP 5120      // per-bucket edge capacity (avg 4082, +16 sigma)
#define B1_EPB 1024   // edges per block in bucket_kernel

typedef __attribute__((ext_vector_type(8))) short bf16x8v;   // 8 bf16 (4 VGPRs)
typedef __attribute__((ext_vector_type(4))) float f32x4v;    // MFMA acc

static __device__ __forceinline__ unsigned short f2bf(float x) {
    union { float f; unsigned u; } v; v.f = x;
    unsigned r = v.u + 0x7fff + ((v.u >> 16) & 1);   // RNE
    return (unsigned short)(r >> 16);
}

// ---------------- B1: coarse bucket scatter (ushort-compressed) ----------------
__global__ __launch_bounds__(256) void bucket_kernel(const int* __restrict__ src,
                                                     const int* __restrict__ dst,
                                                     int* __restrict__ dcur,
                                                     int* __restrict__ scur,
                                                     ushort2* __restrict__ dbucket,
                                                     unsigned short* __restrict__ sbucket) {
    __shared__ int hd[NB], hsb[NB], cd[NB], cs[NB];
    int t = threadIdx.x;
    if (t < NB) { hd[t] = 0; hsb[t] = 0; }
    __syncthreads();
    int d[4], s[4];
    int e0 = blockIdx.x * B1_EPB + t;
    #pragma unroll
    for (int j = 0; j < 4; ++j) {
        int e = e0 + j * 256;
        if (e < NE) {
            d[j] = dst[e]; s[j] = src[e];
            atomicAdd(&hd[d[j] >> 8], 1);
            atomicAdd(&hsb[s[j] >> 8], 1);
        } else d[j] = -1;
    }
    __syncthreads();
    if (t < NB) {
        cd[t] = atomicAdd(&dcur[t], hd[t]);
        cs[t] = atomicAdd(&scur[t], hsb[t]);
    }
    __syncthreads();
    #pragma unroll
    for (int j = 0; j < 4; ++j) {
        if (d[j] >= 0) {
            int b = d[j] >> 8;
            int p = atomicAdd(&cd[b], 1);
            if (p < CAP) dbucket[(long)b * CAP + p] = make_ushort2((unsigned short)d[j],
                                                                   (unsigned short)s[j]);
            int bs = s[j] >> 8;
            int p2 = atomicAdd(&cs[bs], 1);
            if (p2 < CAP) sbucket[(long)bs * CAP + p2] = (unsigned short)s[j];
        }
    }
}

// ---------------- B2+B3 merged: compact CSR (ushort col) + out-degree ----------------
__global__ __launch_bounds__(256) void csr_out_kernel(const ushort2* __restrict__ dbucket,
                                                      const int* __restrict__ dcur,
                                                      const unsigned short* __restrict__ sbucket,
                                                      const int* __restrict__ scur,
                                                      int* __restrict__ row_ptr,
                                                      unsigned short* __restrict__ col,
                                                      int* __restrict__ out_cnt) {
    __shared__ int buf[256];
    __shared__ int hist[256];
    __shared__ int cur[256];
    int k = blockIdx.x, t = threadIdx.x;

    int tot = (t < NB) ? min(dcur[t], CAP) : 0;
    buf[t] = tot;
    __syncthreads();
    for (int o = 1; o < 256; o <<= 1) {
        int a = (t >= o) ? buf[t - o] : 0;
        __syncthreads();
        buf[t] += a;
        __syncthreads();
    }
    int base = (k > 0) ? buf[k - 1] : 0;
    int cnt = min(dcur[k], CAP);

    hist[t] = 0;
    __syncthreads();
    const ushort2* bk = dbucket + (long)k * CAP;
    for (int e = t; e < cnt; e += 256) atomicAdd(&hist[bk[e].x & 255], 1);
    __syncthreads();
    int h = hist[t];

    buf[t] = h;
    __syncthreads();
    for (int o = 1; o < 256; o <<= 1) {
        int a = (t >= o) ? buf[t - o] : 0;
        __syncthreads();
        buf[t] += a;
        __syncthreads();
    }
    int start = base + buf[t] - h;
    int id = (k << 8) + t;
    if (id < NN) row_ptr[id] = start;
    if (k == NB - 1 && t == 0) row_ptr[NN] = base + cnt;
    cur[t] = start;
    __syncthreads();

    for (int e = t; e < cnt; e += 256) {
        ushort2 p = bk[e];
        int pos = atomicAdd(&cur[p.x & 255], 1);
        col[pos] = p.y;
    }

    __syncthreads();
    hist[t] = 0;
    __syncthreads();
    int scnt = min(scur[k], CAP);
    const unsigned short* sk = sbucket + (long)k * CAP;
    for (int e = t; e < scnt; e += 256) atomicAdd(&hist[sk[e] & 255], 1);
    __syncthreads();
    if (id < NN) out_cnt[id] = hist[t];
}

// ---------------- merged node init + weight convert + embsum zero ----------------
__global__ __launch_bounds__(256) void initw_kernel(const float* __restrict__ cx,
                                                    const float* __restrict__ cy,
                                                    const int* __restrict__ row_ptr,
                                                    const int* __restrict__ out_cnt,
                                                    const float* __restrict__ W2,
                                                    const float* __restrict__ W3,
                                                    const float* __restrict__ W4,
                                                    const float* __restrict__ W5,
                                                    float* __restrict__ norm_s,
                                                    float* __restrict__ norm_d,
                                                    float* __restrict__ h0s,
                                                    unsigned short* __restrict__ Wt,
                                                    float* __restrict__ embsum) {
    int bid = blockIdx.x, t = threadIdx.x;
    if (bid < NB) {
        int i = (bid << 8) + t;
        if (i < NN) {
            float id = (float)(row_ptr[i + 1] - row_ptr[i]);
            float od = (float)out_cnt[i];
            float ns = 1.0f / sqrtf(fmaxf(od, 1.0f));
            norm_s[i] = ns;
            norm_d[i] = 1.0f / sqrtf(fmaxf(id, 1.0f));
            h0s[i * 3 + 0] = id * ns;
            h0s[i * 3 + 1] = cx[i] * ns;
            h0s[i * 3 + 2] = cy[i] * ns;
        }
    } else {
        int gid = ((bid - NB) << 8) + t;     // < 65536
        int l = gid >> 14, idx = gid & 16383;
        int n = idx >> 7, k = idx & 127;
        const float* W = (l == 0) ? W2 : (l == 1) ? W3 : (l == 2) ? W4 : W5;
        Wt[gid] = f2bf(W[k * 128 + n]);
        if (bid == NB && t < 128) embsum[t] = 0.0f;
    }
}

// ---------------- layer-1 gather (F=3), compact CSR ----------------
__global__ __launch_bounds__(256) void gather3_kernel(const int* __restrict__ row_ptr,
                                                      const unsigned short* __restrict__ col,
                                                      const float* __restrict__ h0s,
                                                      const float* __restrict__ norm_d,
                                                      float* __restrict__ agg3) {
    int n = blockIdx.x * 256 + threadIdx.x;
    if (n < NN) {
        float a0 = 0.f, a1 = 0.f, a2 = 0.f;
        int end = row_ptr[n + 1];
        for (int e = row_ptr[n]; e < end; ++e) {
            int s = col[e];
            a0 += h0s[s * 3 + 0];
            a1 += h0s[s * 3 + 1];
            a2 += h0s[s * 3 + 2];
        }
        float nd = norm_d[n];
        agg3[n * 3 + 0] = a0 * nd;
        agg3[n * 3 + 1] = a1 * nd;
        agg3[n * 3 + 2] = a2 * nd;
    }
}

// ---------------- layer-1 node (3 -> 128), bf16 dense out, pre-scaled by norm_s ----------------
__global__ __launch_bounds__(256) void node3_kernel(const float* __restrict__ agg3,
                                                    const float* __restrict__ norm_s,
                                                    const float* __restrict__ W1,
                                                    const float* __restrict__ b1,
                                                    unsigned short* __restrict__ h1s) {
    int gid = blockIdx.x * 256 + threadIdx.x;
    int i = gid >> 7, c = gid & 127;
    if (i < NN) {
        float a0 = agg3[i * 3 + 0];
        float a1 = agg3[i * 3 + 1];
        float a2 = agg3[i * 3 + 2];
        float v = a0 * W1[c] + a1 * W1[128 + c] + a2 * W1[256 + c] + b1[c];
        h1s[i * 128 + c] = f2bf(fmaxf(v, 0.0f) * norm_s[i]);
    }
}

// ---------------- FUSED layer (2..4): gather 16 nodes -> LDS A-tile -> MFMA -> bf16 out ----------
// 4 waves/block, 16 nodes/block, 4.3KB LDS, B-frags direct from L2-hot Wt (no staging).
// hin/hout are DISTINCT buffers (ping-pong) -- fused kernel reads all rows, writes own 16.
__global__ __launch_bounds__(256) void fused_layer16_kernel(const int* __restrict__ row_ptr,
                                                            const unsigned short* __restrict__ col,
                                                            const unsigned int* __restrict__ hin,
                                                            const float* __restrict__ norm_d,
                                                            const float* __restrict__ norm_s,
                                                            const unsigned short* __restrict__ Wt,
                                                            const float* __restrict__ bias,
                                                            unsigned short* __restrict__ hout) {
    __shared__ unsigned int lA[16][68];   // packed bf16x2 A-tile; stride 68 dw -> 2-way banks (free)
    int t = threadIdx.x;
    int wv = t >> 6, lane = t & 63;
    int m0 = blockIdx.x << 4;             // 3125 blocks x 16 nodes == 50000 exactly

    // ---- gather phase: wave wv owns rows {wv, 4+wv, 8+wv, 12+wv} ----
    const unsigned int* hb = hin + lane;
    #pragma unroll
    for (int i = 0; i < 4; ++i) {
        int r = (i << 2) + wv;
        int n = m0 + r;
        int beg = row_ptr[n], end = row_ptr[n + 1];
        float nd = norm_d[n];
        float ax = 0.f, ay = 0.f;
        int e = beg;
        for (; e + 7 < end; e += 8) {
            unsigned u[8];
            #pragma unroll
            for (int j = 0; j < 8; ++j) u[j] = hb[(long)col[e + j] << 6];
            #pragma unroll
            for (int j = 0; j < 8; ++j) {
                ax += __uint_as_float(u[j] << 16);
                ay += __uint_as_float(u[j] & 0xffff0000u);
            }
        }
        for (; e < end; ++e) {
            unsigned u0 = hb[(long)col[e] << 6];
            ax += __uint_as_float(u0 << 16);
            ay += __uint_as_float(u0 & 0xffff0000u);
        }
        lA[r][lane] = (unsigned)f2bf(ax * nd) | ((unsigned)f2bf(ay * nd) << 16);
    }
    __syncthreads();

    // ---- GEMM phase: wave wv computes cols [wv*32, wv*32+32) of the 16-row tile ----
    int fr = lane & 15, kq = lane >> 4;
    bf16x8v a0 = *(const bf16x8v*)&lA[fr][ 0 + (kq << 2)];
    bf16x8v a1 = *(const bf16x8v*)&lA[fr][16 + (kq << 2)];
    bf16x8v a2 = *(const bf16x8v*)&lA[fr][32 + (kq << 2)];
    bf16x8v a3 = *(const bf16x8v*)&lA[fr][48 + (kq << 2)];

    float4 scv = *(const float4*)(norm_s + m0 + (kq << 2));   // rows m0+kq*4..+3

    #pragma unroll
    for (int j = 0; j < 2; ++j) {
        int n0 = ((wv << 1) + j) << 4;
        const unsigned short* wb = Wt + ((n0 + fr) << 7) + (kq << 3);
        f32x4v acc = {0.f, 0.f, 0.f, 0.f};
        acc = __builtin_amdgcn_mfma_f32_16x16x32_bf16(a0, *(const bf16x8v*)(wb + 0),  acc, 0, 0, 0);
        acc = __builtin_amdgcn_mfma_f32_16x16x32_bf16(a1, *(const bf16x8v*)(wb + 32), acc, 0, 0, 0);
        acc = __builtin_amdgcn_mfma_f32_16x16x32_bf16(a2, *(const bf16x8v*)(wb + 64), acc, 0, 0, 0);
        acc = __builtin_amdgcn_mfma_f32_16x16x32_bf16(a3, *(const bf16x8v*)(wb + 96), acc, 0, 0, 0);

        int c = n0 + fr;
        float bv = bias[c];
        #pragma unroll
        for (int r = 0; r < 4; ++r) {
            int mr = m0 + (kq << 2) + r;
            float v = fmaxf(acc[r] + bv, 0.f);
            float sc = (r == 0) ? scv.x : (r == 1) ? scv.y : (r == 2) ? scv.z : scv.w;
            hout[((long)mr << 7) + c] = f2bf(v * sc);
        }
    }
}

// ---------------- edge aggregation F=128 (layer 5 only), compact ushort CSR ----------------
__global__ __launch_bounds__(256) void gather_bf16_kernel(const int* __restrict__ row_ptr,
                                                          const unsigned short* __restrict__ col,
                                                          const unsigned int* __restrict__ hs2,
                                                          const float* __restrict__ norm_d,
                                                          unsigned int* __restrict__ aggb2) {
    int t = threadIdx.x;
    int wave = t >> 6;
    int lane = t & 63;
    int n = blockIdx.x * 4 + wave;
    if (n >= NN) return;
    int beg = row_ptr[n], end = row_ptr[n + 1];
    float nd = norm_d[n];
    const unsigned int* hb = hs2 + lane;
    float ax = 0.f, ay = 0.f;
    int e = beg;
    for (; e + 7 < end; e += 8) {
        unsigned u[8];
        #pragma unroll
        for (int j = 0; j < 8; ++j) u[j] = hb[(long)col[e + j] << 6];
        #pragma unroll
        for (int j = 0; j < 8; ++j) {
            ax += __uint_as_float(u[j] << 16);
            ay += __uint_as_float(u[j] & 0xffff0000u);
        }
    }
    for (; e < end; ++e) {
        unsigned u0 = hb[(long)col[e] << 6];
        ax += __uint_as_float(u0 << 16);
        ay += __uint_as_float(u0 & 0xffff0000u);
    }
    unsigned po = (unsigned)f2bf(ax * nd) | ((unsigned)f2bf(ay * nd) << 16);
    aggb2[(n << 6) + lane] = po;
}

// ---------------- layer-5 GEMM via MFMA (fp32 out to d_out + fused colsum) ----------------
__global__ __launch_bounds__(256) void gemm_mfma_kernel(const unsigned short* __restrict__ aggb,
                                                        const unsigned short* __restrict__ Wt,
                                                        const float* __restrict__ bias,
                                                        float* __restrict__ out_f32,
                                                        float* __restrict__ embsum) {
    __shared__ unsigned short ldsw[128][136];
    __shared__ float ldscol[4][4][128];

    int t = threadIdx.x;
    int wv = t >> 6, lane = t & 63;
    int fr = lane & 15, kq = lane >> 4;
    int m0 = blockIdx.x * 64 + wv * 16;

    #pragma unroll
    for (int i = 0; i < 8; ++i) {
        int idx = t + 256 * i;
        int r = idx >> 4;
        int c8 = (idx & 15) << 3;
        *(bf16x8v*)(&ldsw[r][c8]) = *(const bf16x8v*)(Wt + (r << 7) + c8);
    }

    int mrow = m0 + fr;
    long abase = (long)((mrow < NN) ? mrow : 0) << 7;
    bf16x8v a0 = *(const bf16x8v*)(aggb + abase + 0  + kq * 8);
    bf16x8v a1 = *(const bf16x8v*)(aggb + abase + 32 + kq * 8);
    bf16x8v a2 = *(const bf16x8v*)(aggb + abase + 64 + kq * 8);
    bf16x8v a3 = *(const bf16x8v*)(aggb + abase + 96 + kq * 8);

    __syncthreads();

    #pragma unroll
    for (int nt = 0; nt < 8; ++nt) {
        int n0 = nt << 4;
        f32x4v acc = {0.f, 0.f, 0.f, 0.f};
        acc = __builtin_amdgcn_mfma_f32_16x16x32_bf16(a0, *(const bf16x8v*)(&ldsw[n0 + fr][0  + kq * 8]), acc, 0, 0, 0);
        acc = __builtin_amdgcn_mfma_f32_16x16x32_bf16(a1, *(const bf16x8v*)(&ldsw[n0 + fr][32 + kq * 8]), acc, 0, 0, 0);
        acc = __builtin_amdgcn_mfma_f32_16x16x32_bf16(a2, *(const bf16x8v*)(&ldsw[n0 + fr][64 + kq * 8]), acc, 0, 0, 0);
        acc = __builtin_amdgcn_mfma_f32_16x16x32_bf16(a3, *(const bf16x8v*)(&ldsw[n0 + fr][96 + kq * 8]), acc, 0, 0, 0);

        int c = n0 + fr;
        float bv = bias[c];
        float cs = 0.f;
        #pragma unroll
        for (int r = 0; r < 4; ++r) {
            int mr = m0 + kq * 4 + r;
            if (mr < NN) {
                float v = fmaxf(acc[r] + bv, 0.f);
                out_f32[((long)mr << 7) + c] = v;
                cs += v;
            }
        }
        ldscol[wv][kq][c] = cs;
    }

    __syncthreads();
    if (t < 128) {
        float s = 0.f;
        #pragma unroll
        for (int w = 0; w < 4; ++w)
            #pragma unroll
            for (int q = 0; q < 4; ++q)
                s += ldscol[w][q][t];
        atomicAdd(&embsum[t], s);
    }
}

// ---------------- head MLP ----------------
__global__ __launch_bounds__(128) void head_kernel(const float* __restrict__ embsum,
                                                   const float* __restrict__ Wl1,
                                                   const float* __restrict__ bl1,
                                                   const float* __restrict__ Wl2,
                                                   const float* __restrict__ bl2,
                                                   float* __restrict__ d_out) {
    __shared__ float emb[128];
    __shared__ float hemb[64];
    int t = threadIdx.x;
    float e = embsum[t] * (1.0f / (float)NN);
    emb[t] = e;
    d_out[1 + t] = e;
    __syncthreads();
    if (t < 64) {
        float acc = bl1[t];
        for (int k = 0; k < 128; ++k)
            acc += emb[k] * Wl1[k * 64 + t];
        hemb[t] = fmaxf(acc, 0.f);
    }
    __syncthreads();
    if (t == 0) {
        float acc = bl2[0];
        for (int j = 0; j < 64; ++j)
            acc += hemb[j] * Wl2[j];
        d_out[0] = 1.0f / (1.0f + expf(-acc));
    }
}

extern "C" void kernel_launch(void* const* d_in, const int* in_sizes, int n_in,
                              void* d_out, int out_size, void* d_ws, size_t ws_size,
                              hipStream_t stream) {
    const float* cx  = (const float*)d_in[0];
    const float* cy  = (const float*)d_in[1];
    const float* W1  = (const float*)d_in[2];
    const float* b1  = (const float*)d_in[3];
    const float* W2  = (const float*)d_in[4];
    const float* b2  = (const float*)d_in[5];
    const float* W3  = (const float*)d_in[6];
    const float* b3  = (const float*)d_in[7];
    const float* W4  = (const float*)d_in[8];
    const float* b4  = (const float*)d_in[9];
    const float* W5  = (const float*)d_in[10];
    const float* b5  = (const float*)d_in[11];
    const float* Wl1 = (const float*)d_in[12];
    const float* bl1 = (const float*)d_in[13];
    const float* Wl2 = (const float*)d_in[14];
    const float* bl2 = (const float*)d_in[15];
    const int*   src = (const int*)d_in[16];
    const int*   dst = (const int*)d_in[17];

    float* out = (float*)d_out;
    float* h_out = out + 129;

    // workspace layout (float-index units)
    float* ws       = (float*)d_ws;
    float* norm_s   = ws;                                   // N
    float* norm_d   = ws + NN;                              // N
    int*   out_cnt  = (int*)(ws + 2 * NN);                  // N
    int*   row_ptr  = (int*)(ws + 3 * NN);                  // N+1
    unsigned short* hsA = (unsigned short*)(ws + 4 * NN + 64);    // 128N bf16
    unsigned short* hsB = (unsigned short*)(ws + 68 * NN + 64);   // 128N bf16
    unsigned short* col = (unsigned short*)(ws + 132 * NN + 64);  // NE ushort
    float* h0s      = ws + 148 * NN + 64;                   // 3N
    float* agg3     = ws + 151 * NN + 64;                   // 3N
    unsigned short* Wt = (unsigned short*)(ws + 154 * NN + 64);   // 4*16384 bf16
    float* embsum   = ws + 154 * NN + 64 + 32768;           // 128
    int*   dcur     = (int*)(ws + 154 * NN + 33600);        // NB
    int*   scur     = dcur + NB;                            // NB
    ushort2* dbucket = (ushort2*)(ws + 154 * NN + 34048);   // NB*CAP ushort2 (= NB*CAP fl)
    unsigned short* sbucket = (unsigned short*)(ws + 154 * NN + 34048 + NB * CAP);

    // 1. two-level bucket CSR build (atomic-light, ushort-compressed)
    hipMemsetAsync(dcur, 0, 2 * NB * sizeof(int), stream);
    bucket_kernel<<<(NE + B1_EPB - 1) / B1_EPB, 256, 0, stream>>>(src, dst, dcur, scur,
                                                                  dbucket, sbucket);
    csr_out_kernel<<<NB, 256, 0, stream>>>(dbucket, dcur, sbucket, scur,
                                           row_ptr, col, out_cnt);

    // 2. norms + scaled h0 + weight convert + embsum zero (merged)
    initw_kernel<<<NB + 256, 256, 0, stream>>>(cx, cy, row_ptr, out_cnt,
                                               W2, W3, W4, W5,
                                               norm_s, norm_d, h0s, Wt, embsum);

    // 3. layer 1 (F_in = 3) -> hsA
    gather3_kernel<<<(NN + 255) / 256, 256, 0, stream>>>(row_ptr, col, h0s, norm_d, agg3);
    node3_kernel<<<(NN * 128) / 256, 256, 0, stream>>>(agg3, norm_s, W1, b1, hsA);

    // 4. layers 2..4: fused gather+MFMA, ping-pong hsA/hsB
    const float* bs[3] = {b2, b3, b4};
    unsigned short* hcur = hsA;
    unsigned short* hnxt = hsB;
    for (int l = 0; l < 3; ++l) {
        fused_layer16_kernel<<<NN / 16, 256, 0, stream>>>(row_ptr, col,
                                                          (const unsigned int*)hcur,
                                                          norm_d, norm_s,
                                                          Wt + l * 16384, bs[l], hnxt);
        unsigned short* tmp = hcur; hcur = hnxt; hnxt = tmp;
    }

    // 5. layer 5: proven split path (gather -> aggb in hnxt, MFMA -> fp32 h_out + colsum)
    gather_bf16_kernel<<<(NN + 3) / 4, 256, 0, stream>>>(row_ptr, col,
                                                         (const unsigned int*)hcur,
                                                         norm_d,
                                                         (unsigned int*)hnxt);
    gemm_mfma_kernel<<<(NN + 63) / 64, 256, 0, stream>>>(hnxt, Wt + 3 * 16384, b5,
                                                         h_out, embsum);

    // 6. head
    head_kernel<<<1, 128, 0, stream>>>(embsum, Wl1, bl1, Wl2, bl2, out);
}